// Round 3
// baseline (382.693 us; speedup 1.0000x reference)
//
#include <hip/hip_runtime.h>
#include <math.h>

#define B_    4
#define S_    2048
#define BS_   8192       // B_*S_
#define DM_   1024
#define DS_   256
#define LB_   64
#define TOPK_ 8

typedef __bf16 bf16x8 __attribute__((ext_vector_type(8)));
typedef float  f32x4  __attribute__((ext_vector_type(4)));

static __device__ __forceinline__ unsigned short f2bf(float f) {
    union { float f; unsigned u; } a; a.f = f;
    unsigned u = a.u;
    unsigned r = u + 0x7FFFu + ((u >> 16) & 1u);   // RNE
    return (unsigned short)(r >> 16);
}
static __device__ __forceinline__ unsigned pack2(float a, float b) {
    return (unsigned)f2bf(a) | ((unsigned)f2bf(b) << 16);
}
// granule swizzle: 16B granule index within a 64B row
static __device__ __forceinline__ int swz(int row, int cb) {
    return (cb ^ (row & 3) ^ ((row >> 2) & 3)) & 3;
}

// ---------------------------------------------------------------------------
// MFMA bf16 GEMM: C[M,N] = epi(A_f32[M,K] @ Bt_bf16[N,K]^T + bias[N])
// MF = M-fragments per wave (2 -> BM=64, 4 -> BM=128). BN=64, BK=32.
// 256 threads = 4 waves (2x2), wave tile (MF*16) x 32.
// EPI: 0 none | 2 h-update: C=extra0+val*extra1[m] | 3 addx: C=extra0+val
// ---------------------------------------------------------------------------
template<int MF, int EPI>
__global__ __launch_bounds__(256) void mm_k(
    const float* __restrict__ A, const unsigned short* __restrict__ Bt,
    const float* __restrict__ bias, float* __restrict__ C,
    int M, int K, int N,
    const float* __restrict__ extra0, const float* __restrict__ extra1)
{
    constexpr int BM = MF * 32;
    __shared__ unsigned char smem[BM * 64 + 4096];
    unsigned char* smA = smem;
    unsigned char* smB = smem + BM * 64;

    const int tid  = threadIdx.x;
    const int lane = tid & 63;
    const int wid  = tid >> 6;
    const int wm   = wid >> 1, wn = wid & 1;
    const int bm   = blockIdx.y * BM, bn = blockIdx.x * 64;
    const int lr   = lane & 15, lc = lane >> 4;

    f32x4 acc[MF][2] = {};

    for (int k0 = 0; k0 < K; k0 += 32) {
        // stage A: BM rows x 4 granules
        #pragma unroll
        for (int i = 0; i < MF / 2; ++i) {
            int e = tid + i * 256;
            int row = e >> 2, cb = e & 3;
            const float* src = A + (size_t)(bm + row) * K + k0 + cb * 8;
            float4 u = *reinterpret_cast<const float4*>(src);
            float4 w = *reinterpret_cast<const float4*>(src + 4);
            uint4 g;
            g.x = pack2(u.x, u.y); g.y = pack2(u.z, u.w);
            g.z = pack2(w.x, w.y); g.w = pack2(w.z, w.w);
            *reinterpret_cast<uint4*>(smA + row * 64 + swz(row, cb) * 16) = g;
        }
        // stage B: 64 rows x 4 granules
        {
            int row = tid >> 2, cb = tid & 3;
            uint4 g = *reinterpret_cast<const uint4*>(
                Bt + (size_t)(bn + row) * K + k0 + cb * 8);
            *reinterpret_cast<uint4*>(smB + row * 64 + swz(row, cb) * 16) = g;
        }
        __syncthreads();

        bf16x8 af[MF], bfr[2];
        #pragma unroll
        for (int i = 0; i < MF; ++i) {
            int m = wm * (MF * 16) + i * 16 + lr;
            af[i] = *reinterpret_cast<const bf16x8*>(smA + m * 64 + swz(m, lc) * 16);
        }
        #pragma unroll
        for (int j = 0; j < 2; ++j) {
            int n = wn * 32 + j * 16 + lr;
            bfr[j] = *reinterpret_cast<const bf16x8*>(smB + n * 64 + swz(n, lc) * 16);
        }
        #pragma unroll
        for (int i = 0; i < MF; ++i)
            #pragma unroll
            for (int j = 0; j < 2; ++j)
                acc[i][j] = __builtin_amdgcn_mfma_f32_16x16x32_bf16(
                    af[i], bfr[j], acc[i][j], 0, 0, 0);
        __syncthreads();
    }

    #pragma unroll
    for (int i = 0; i < MF; ++i) {
        #pragma unroll
        for (int j = 0; j < 2; ++j) {
            int col = bn + wn * 32 + j * 16 + lr;
            #pragma unroll
            for (int r = 0; r < 4; ++r) {
                int row = bm + wm * (MF * 16) + i * 16 + lc * 4 + r;
                float val = acc[i][j][r] + bias[col];
                if (EPI == 2)      val = extra0[(size_t)row * N + col] + val * extra1[row];
                else if (EPI == 3) val = extra0[(size_t)row * N + col] + val;
                C[(size_t)row * N + col] = val;
            }
        }
    }
}

// ---------------------------------------------------------------------------
// ui-concat MFMA GEMM + tanh: t = tanh([h|mixed|pb|summ] @ W1 + b1)
// K=1024 (4 segments of 256), pb[m,:] = php[m>>4,:]. N=256, M=8192. BM=64.
// ---------------------------------------------------------------------------
__global__ __launch_bounds__(256) void mm_ui_k(
    const float* __restrict__ h, const float* __restrict__ mixed,
    const float* __restrict__ php, const float* __restrict__ summ,
    const unsigned short* __restrict__ W1t, const float* __restrict__ b1,
    float* __restrict__ t)
{
    __shared__ unsigned char smem[8192];
    unsigned char* smA = smem;
    unsigned char* smB = smem + 4096;

    const int tid  = threadIdx.x;
    const int lane = tid & 63;
    const int wid  = tid >> 6;
    const int wm   = wid >> 1, wn = wid & 1;
    const int bm   = blockIdx.y * 64, bn = blockIdx.x * 64;
    const int lr   = lane & 15, lc = lane >> 4;

    f32x4 acc[2][2] = {};

    for (int k0 = 0; k0 < 1024; k0 += 32) {
        const int seg = k0 >> 8, kb = k0 & 255;
        const float* Asrc = (seg == 0) ? h : (seg == 1) ? mixed : (seg == 2) ? php : summ;
        {
            int row = tid >> 2, cb = tid & 3;
            int rs = bm + row;
            if (seg == 2) rs >>= 4;
            const float* src = Asrc + (size_t)rs * DS_ + kb + cb * 8;
            float4 u = *reinterpret_cast<const float4*>(src);
            float4 w = *reinterpret_cast<const float4*>(src + 4);
            uint4 g;
            g.x = pack2(u.x, u.y); g.y = pack2(u.z, u.w);
            g.z = pack2(w.x, w.y); g.w = pack2(w.z, w.w);
            *reinterpret_cast<uint4*>(smA + row * 64 + swz(row, cb) * 16) = g;
        }
        {
            int row = tid >> 2, cb = tid & 3;
            uint4 g = *reinterpret_cast<const uint4*>(
                W1t + (size_t)(bn + row) * 1024 + k0 + cb * 8);
            *reinterpret_cast<uint4*>(smB + row * 64 + swz(row, cb) * 16) = g;
        }
        __syncthreads();

        bf16x8 af[2], bfr[2];
        #pragma unroll
        for (int i = 0; i < 2; ++i) {
            int m = wm * 32 + i * 16 + lr;
            af[i] = *reinterpret_cast<const bf16x8*>(smA + m * 64 + swz(m, lc) * 16);
        }
        #pragma unroll
        for (int j = 0; j < 2; ++j) {
            int n = wn * 32 + j * 16 + lr;
            bfr[j] = *reinterpret_cast<const bf16x8*>(smB + n * 64 + swz(n, lc) * 16);
        }
        #pragma unroll
        for (int i = 0; i < 2; ++i)
            #pragma unroll
            for (int j = 0; j < 2; ++j)
                acc[i][j] = __builtin_amdgcn_mfma_f32_16x16x32_bf16(
                    af[i], bfr[j], acc[i][j], 0, 0, 0);
        __syncthreads();
    }

    #pragma unroll
    for (int i = 0; i < 2; ++i) {
        #pragma unroll
        for (int j = 0; j < 2; ++j) {
            int col = bn + wn * 32 + j * 16 + lr;
            #pragma unroll
            for (int r = 0; r < 4; ++r) {
                int row = bm + wm * 32 + i * 16 + lc * 4 + r;
                t[(size_t)row * DS_ + col] = tanhf(acc[i][j][r] + b1[col]);
            }
        }
    }
}

// ---------------------------------------------------------------------------
// Weight prep: out_bf16[N][K] = bf16(in_f32[K][N])  (32x32 LDS tile transpose)
// ---------------------------------------------------------------------------
__global__ __launch_bounds__(256) void transpose_cvt_k(
    const float* __restrict__ in, unsigned short* __restrict__ out, int K, int N)
{
    __shared__ float t[32][33];
    const int k0 = blockIdx.y * 32, n0 = blockIdx.x * 32;
    const int tx = threadIdx.x & 31, ty = threadIdx.x >> 5;
    #pragma unroll
    for (int r = 0; r < 32; r += 8)
        t[ty + r][tx] = in[(size_t)(k0 + ty + r) * N + n0 + tx];
    __syncthreads();
    #pragma unroll
    for (int r = 0; r < 32; r += 8)
        out[(size_t)(n0 + ty + r) * K + k0 + tx] = f2bf(t[tx][ty + r]);
}

__global__ __launch_bounds__(256) void biascat_k(
    const float* __restrict__ bq, const float* __restrict__ bk,
    const float* __restrict__ bv, float* __restrict__ bqkv)
{
    int i = blockIdx.x * 256 + threadIdx.x;
    if (i < 768) {
        float v = (i < 256) ? bq[i] : (i < 512) ? bk[i - 256] : bv[i - 512];
        bqkv[i] = v;
    }
}

// ---------------------------------------------------------------------------
// Causal depthwise conv (K=5) + chunk mean. One block per (b, chunk of 16).
// ---------------------------------------------------------------------------
__global__ __launch_bounds__(256) void conv_pool_k(
    const float* __restrict__ h, const float* __restrict__ conv_w,
    const float* __restrict__ conv_b, float* __restrict__ mixed,
    float* __restrict__ cmean)
{
    const int blk = blockIdx.x;          // b*128 + c
    const int d = threadIdx.x;
    const int b = blk >> 7;
    const int s0 = (blk & 127) * 16;
    const float* hb = h + (size_t)b * S_ * DS_;
    float* mb = mixed + (size_t)b * S_ * DS_;

    const float w0 = conv_w[0 * DS_ + d], w1 = conv_w[1 * DS_ + d],
                w2 = conv_w[2 * DS_ + d], w3 = conv_w[3 * DS_ + d],
                w4 = conv_w[4 * DS_ + d];
    const float cb = conv_b[d];

    float a0 = (s0 >= 4) ? hb[(size_t)(s0 - 4) * DS_ + d] : 0.f;
    float a1 = (s0 >= 3) ? hb[(size_t)(s0 - 3) * DS_ + d] : 0.f;
    float a2 = (s0 >= 2) ? hb[(size_t)(s0 - 2) * DS_ + d] : 0.f;
    float a3 = (s0 >= 1) ? hb[(size_t)(s0 - 1) * DS_ + d] : 0.f;

    float sum = 0.f;
    #pragma unroll
    for (int tt = 0; tt < 16; ++tt) {
        int s = s0 + tt;
        float cur = hb[(size_t)s * DS_ + d];
        mb[(size_t)s * DS_ + d] = w0 * a0 + w1 * a1 + w2 * a2 + w3 * a3 + w4 * cur + cb;
        sum += cur;
        a0 = a1; a1 = a2; a2 = a3; a3 = cur;
    }
    cmean[(size_t)blk * DS_ + d] = sum * (1.f / 16.f);
}

// ---------------------------------------------------------------------------
// Halt gate: gate[m] = sigmoid(h[m,:]·Wh[:,2] + bh[2]). 4 tokens / block.
// ---------------------------------------------------------------------------
__global__ __launch_bounds__(256) void gate_k(
    const float* __restrict__ h, const float* __restrict__ Wh,
    const float* __restrict__ bh, float* __restrict__ gate)
{
    const int m = blockIdx.x * 4 + (threadIdx.x >> 6);
    const int lane = threadIdx.x & 63;
    const float* hr = h + (size_t)m * DS_;
    float p = 0.f;
    for (int j = lane; j < DS_; j += 64) p += hr[j] * Wh[j * 3 + 2];
    #pragma unroll
    for (int off = 32; off; off >>= 1) p += __shfl_down(p, off);
    if (lane == 0) gate[m] = 1.f / (1.f + expf(-(p + bh[2])));
}

// ---------------------------------------------------------------------------
// Windowed causal top-8 attention, reading fused qkv[M][768].
// 4 waves/block = 4 tokens; one wave per token. ILP-8 dot; butterfly argmax
// x8 (low-index tie-break). XCD-swizzled grid: each XCD owns a contiguous
// 1024-token range so the K/V window stays in its 4MB L2.
// ---------------------------------------------------------------------------
__global__ __launch_bounds__(256) void attn_k(
    const float* __restrict__ qkv, float* __restrict__ summ)
{
    const int bid = blockIdx.x;                       // 2048 blocks
    const int sb  = (bid & 7) * 256 + (bid >> 3);     // bijective XCD swizzle
    const int m   = sb * 4 + (threadIdx.x >> 6);
    const int b = m >> 11;
    const int s = m & (S_ - 1);
    const int lane = threadIdx.x & 63;

    const float4* q4 = reinterpret_cast<const float4*>(qkv + (size_t)m * 768);
    const int row = s - LB_ + lane;

    float sc = -INFINITY;
    if (row >= 0) {
        const float4* k4 = reinterpret_cast<const float4*>(
            qkv + ((size_t)(b * S_) + row) * 768 + 256);
        float p0 = 0.f, p1 = 0.f, p2 = 0.f, p3 = 0.f;
        float p4 = 0.f, p5 = 0.f, p6 = 0.f, p7 = 0.f;
        #pragma unroll 8
        for (int j = 0; j < 64; j += 2) {
            float4 a = q4[j],     c = k4[j];
            float4 e = q4[j + 1], f = k4[j + 1];
            p0 += a.x * c.x; p1 += a.y * c.y; p2 += a.z * c.z; p3 += a.w * c.w;
            p4 += e.x * f.x; p5 += e.y * f.y; p6 += e.z * f.z; p7 += e.w * f.w;
        }
        sc = (((p0 + p1) + (p2 + p3)) + ((p4 + p5) + (p6 + p7))) * 0.0625f;
    }

    float vals[TOPK_]; int idxs[TOPK_];
    #pragma unroll
    for (int t = 0; t < TOPK_; ++t) {
        float mv = sc; int mi = lane;
        #pragma unroll
        for (int off = 32; off; off >>= 1) {
            float ov = __shfl_xor(mv, off);
            int   oi = __shfl_xor(mi, off);
            if (ov > mv || (ov == mv && oi < mi)) { mv = ov; mi = oi; }
        }
        vals[t] = mv; idxs[t] = mi;
        if (lane == mi) sc = -INFINITY;
    }

    const float mref = (vals[0] == -INFINITY) ? 0.f : vals[0];
    float e[TOPK_], ssum = 0.f;
    #pragma unroll
    for (int t = 0; t < TOPK_; ++t) { e[t] = expf(vals[t] - mref); ssum += e[t]; }
    const float inv = 1.f / fmaxf(ssum, 1e-30f);

    float out[4] = {0.f, 0.f, 0.f, 0.f};
    #pragma unroll
    for (int t = 0; t < TOPK_; ++t) {
        float wt = e[t] * inv;
        int tok = s - LB_ + idxs[t];
        tok = min(max(tok, 0), S_ - 1);
        const float* vr = qkv + ((size_t)(b * S_) + tok) * 768 + 512;
        #pragma unroll
        for (int i = 0; i < 4; ++i) out[i] += wt * vr[lane + i * 64];
    }
    #pragma unroll
    for (int i = 0; i < 4; ++i)
        summ[(size_t)m * DS_ + lane + i * 64] = out[i];
}

// ---------------------------------------------------------------------------
extern "C" void kernel_launch(void* const* d_in, const int* in_sizes, int n_in,
                              void* d_out, int out_size, void* d_ws, size_t ws_size,
                              hipStream_t stream)
{
    const float* x      = (const float*)d_in[0];
    const float* Wi     = (const float*)d_in[1];
    const float* bi     = (const float*)d_in[2];
    const float* conv_w = (const float*)d_in[3];
    const float* conv_b = (const float*)d_in[4];
    const float* Wp     = (const float*)d_in[5];
    const float* bp     = (const float*)d_in[6];
    const float* Wh     = (const float*)d_in[7];
    const float* bh     = (const float*)d_in[8];
    const float* Wq     = (const float*)d_in[9];
    const float* bq     = (const float*)d_in[10];
    const float* Wk     = (const float*)d_in[11];
    const float* bk     = (const float*)d_in[12];
    const float* Wv     = (const float*)d_in[13];
    const float* bv     = (const float*)d_in[14];
    const float* W1     = (const float*)d_in[15];
    const float* b1     = (const float*)d_in[16];
    const float* W2     = (const float*)d_in[17];
    const float* b2     = (const float*)d_in[18];
    const float* Wo     = (const float*)d_in[19];
    const float* bo     = (const float*)d_in[20];
    float* out = (float*)d_out;

    float* F     = (float*)d_ws;
    float* h     = F;                            // 8192*256
    float* mixed = h     + (size_t)BS_ * DS_;    // 8192*256
    float* qkv   = mixed + (size_t)BS_ * DS_;    // 8192*768
    float* sm    = qkv   + (size_t)BS_ * 768;    // 8192*256
    float* tb    = sm    + (size_t)BS_ * DS_;    // 8192*256
    float* cmean = tb    + (size_t)BS_ * DS_;    // 512*256
    float* php   = cmean + (size_t)512 * DS_;    // 512*256
    float* gate  = php   + (size_t)512 * DS_;    // 8192
    float* bqkv  = gate  + BS_;                  // 768
    unsigned short* U = (unsigned short*)(bqkv + 768);
    unsigned short* Wit   = U;                          // 256 x 1024
    unsigned short* Wqkvt = Wit   + (size_t)256 * 1024; // 768 x 256
    unsigned short* Wpt   = Wqkvt + (size_t)768 * 256;  // 256 x 256
    unsigned short* W1t   = Wpt   + (size_t)256 * 256;  // 256 x 1024
    unsigned short* W2t   = W1t   + (size_t)256 * 1024; // 256 x 256
    unsigned short* Wot   = W2t   + (size_t)256 * 256;  // 1024 x 256

    dim3 blk(256);

    // ---- weight prep ----
    transpose_cvt_k<<<dim3(256 / 32, 1024 / 32), blk, 0, stream>>>(Wi, Wit, 1024, 256);
    transpose_cvt_k<<<dim3(256 / 32, 256 / 32),  blk, 0, stream>>>(Wq, Wqkvt,              256, 256);
    transpose_cvt_k<<<dim3(256 / 32, 256 / 32),  blk, 0, stream>>>(Wk, Wqkvt + 256 * 256,  256, 256);
    transpose_cvt_k<<<dim3(256 / 32, 256 / 32),  blk, 0, stream>>>(Wv, Wqkvt + 512 * 256,  256, 256);
    transpose_cvt_k<<<dim3(256 / 32, 256 / 32),  blk, 0, stream>>>(Wp, Wpt, 256, 256);
    transpose_cvt_k<<<dim3(256 / 32, 1024 / 32), blk, 0, stream>>>(W1, W1t, 1024, 256);
    transpose_cvt_k<<<dim3(256 / 32, 256 / 32),  blk, 0, stream>>>(W2, W2t, 256, 256);
    transpose_cvt_k<<<dim3(1024 / 32, 256 / 32), blk, 0, stream>>>(Wo, Wot, 256, 1024);
    biascat_k<<<3, blk, 0, stream>>>(bq, bk, bv, bqkv);

    // ---- forward ----
    // h = x @ Wi + bi          (BM=64 -> 512 blocks, 2/CU)
    mm_k<2, 0><<<dim3(4, 128), blk, 0, stream>>>(x, Wit, bi, h, BS_, DM_, DS_, nullptr, nullptr);

    for (int step = 0; step < 2; ++step) {
        conv_pool_k<<<512, blk, 0, stream>>>(h, conv_w, conv_b, mixed, cmean);
        mm_k<2, 0><<<dim3(4, 8), blk, 0, stream>>>(cmean, Wpt, bp, php, 512, DS_, DS_, nullptr, nullptr);
        // qkv: N=768, BM=128 -> 768 blocks
        mm_k<4, 0><<<dim3(12, 64), blk, 0, stream>>>(h, Wqkvt, bqkv, qkv, BS_, DS_, 768, nullptr, nullptr);
        gate_k<<<BS_ / 4, blk, 0, stream>>>(h, Wh, bh, gate);
        attn_k<<<2048, blk, 0, stream>>>(qkv, sm);
        mm_ui_k<<<dim3(4, 128), blk, 0, stream>>>(h, mixed, php, sm, W1t, b1, tb);
        // h = h + (tanh(ui@W1+b1) @ W2 + b2) * gate   (BM=64)
        mm_k<2, 2><<<dim3(4, 128), blk, 0, stream>>>(tb, W2t, b2, h, BS_, DS_, DS_, h, gate);
    }

    // out = x + h @ Wo + bo    (BM=128 -> 1024 blocks)
    mm_k<4, 3><<<dim3(16, 64), blk, 0, stream>>>(h, Wot, bo, out, BS_, DS_, DM_, x, nullptr);
}

// Round 4
// 259.826 us; speedup vs baseline: 1.4729x; 1.4729x over previous
//
#include <hip/hip_runtime.h>
#include <math.h>

#define B_    4
#define S_    2048
#define BS_   8192       // B_*S_
#define DM_   1024
#define DS_   256
#define LB_   64
#define TOPK_ 8

typedef __bf16 bf16x8 __attribute__((ext_vector_type(8)));
typedef float  f32x4  __attribute__((ext_vector_type(4)));

static __device__ __forceinline__ unsigned short f2bf(float f) {
    union { float f; unsigned u; } a; a.f = f;
    unsigned u = a.u;
    unsigned r = u + 0x7FFFu + ((u >> 16) & 1u);   // RNE
    return (unsigned short)(r >> 16);
}
static __device__ __forceinline__ unsigned pack2(float a, float b) {
    return (unsigned)f2bf(a) | ((unsigned)f2bf(b) << 16);
}
// granule swizzle: 16B granule index within a 64B row
static __device__ __forceinline__ int swz(int row, int cb) {
    return (cb ^ (row & 3) ^ ((row >> 2) & 3)) & 3;
}

// ---------------------------------------------------------------------------
// MFMA bf16 GEMM: C[M,N] = epi(A_f32[M,K] @ Bt_bf16[N,K]^T + bias[N])
// MF = M-fragments per wave (2 -> BM=64, 4 -> BM=128). BN=64, BK=32.
// EPI: 0 none | 2 h-update: C=extra0+val*extra1[m] | 3 addx: C=extra0+val
// ---------------------------------------------------------------------------
template<int MF, int EPI>
__global__ __launch_bounds__(256) void mm_k(
    const float* __restrict__ A, const unsigned short* __restrict__ Bt,
    const float* __restrict__ bias, float* __restrict__ C,
    int M, int K, int N,
    const float* __restrict__ extra0, const float* __restrict__ extra1)
{
    constexpr int BM = MF * 32;
    __shared__ __align__(16) unsigned char smem[BM * 64 + 4096];
    unsigned char* smA = smem;
    unsigned char* smB = smem + BM * 64;

    const int tid  = threadIdx.x;
    const int lane = tid & 63;
    const int wid  = tid >> 6;
    const int wm   = wid >> 1, wn = wid & 1;
    const int bm   = blockIdx.y * BM, bn = blockIdx.x * 64;
    const int lr   = lane & 15, lc = lane >> 4;

    f32x4 acc[MF][2] = {};

    for (int k0 = 0; k0 < K; k0 += 32) {
        #pragma unroll
        for (int i = 0; i < MF / 2; ++i) {
            int e = tid + i * 256;
            int row = e >> 2, cb = e & 3;
            const float* src = A + (size_t)(bm + row) * K + k0 + cb * 8;
            float4 u = *reinterpret_cast<const float4*>(src);
            float4 w = *reinterpret_cast<const float4*>(src + 4);
            uint4 g;
            g.x = pack2(u.x, u.y); g.y = pack2(u.z, u.w);
            g.z = pack2(w.x, w.y); g.w = pack2(w.z, w.w);
            *reinterpret_cast<uint4*>(smA + row * 64 + swz(row, cb) * 16) = g;
        }
        {
            int row = tid >> 2, cb = tid & 3;
            uint4 g = *reinterpret_cast<const uint4*>(
                Bt + (size_t)(bn + row) * K + k0 + cb * 8);
            *reinterpret_cast<uint4*>(smB + row * 64 + swz(row, cb) * 16) = g;
        }
        __syncthreads();

        bf16x8 af[MF], bfr[2];
        #pragma unroll
        for (int i = 0; i < MF; ++i) {
            int m = wm * (MF * 16) + i * 16 + lr;
            af[i] = *reinterpret_cast<const bf16x8*>(smA + m * 64 + swz(m, lc) * 16);
        }
        #pragma unroll
        for (int j = 0; j < 2; ++j) {
            int n = wn * 32 + j * 16 + lr;
            bfr[j] = *reinterpret_cast<const bf16x8*>(smB + n * 64 + swz(n, lc) * 16);
        }
        #pragma unroll
        for (int i = 0; i < MF; ++i)
            #pragma unroll
            for (int j = 0; j < 2; ++j)
                acc[i][j] = __builtin_amdgcn_mfma_f32_16x16x32_bf16(
                    af[i], bfr[j], acc[i][j], 0, 0, 0);
        __syncthreads();
    }

    #pragma unroll
    for (int i = 0; i < MF; ++i) {
        #pragma unroll
        for (int j = 0; j < 2; ++j) {
            int col = bn + wn * 32 + j * 16 + lr;
            #pragma unroll
            for (int r = 0; r < 4; ++r) {
                int row = bm + wm * (MF * 16) + i * 16 + lc * 4 + r;
                float val = acc[i][j][r] + bias[col];
                if (EPI == 2)      val = extra0[(size_t)row * N + col] + val * extra1[row];
                else if (EPI == 3) val = extra0[(size_t)row * N + col] + val;
                C[(size_t)row * N + col] = val;
            }
        }
    }
}

// ---------------------------------------------------------------------------
// ui-concat MFMA GEMM + tanh: t = tanh([h|mixed|pb|summ] @ W1 + b1)
// ---------------------------------------------------------------------------
__global__ __launch_bounds__(256) void mm_ui_k(
    const float* __restrict__ h, const float* __restrict__ mixed,
    const float* __restrict__ php, const float* __restrict__ summ,
    const unsigned short* __restrict__ W1t, const float* __restrict__ b1,
    float* __restrict__ t)
{
    __shared__ __align__(16) unsigned char smem[8192];
    unsigned char* smA = smem;
    unsigned char* smB = smem + 4096;

    const int tid  = threadIdx.x;
    const int lane = tid & 63;
    const int wid  = tid >> 6;
    const int wm   = wid >> 1, wn = wid & 1;
    const int bm   = blockIdx.y * 64, bn = blockIdx.x * 64;
    const int lr   = lane & 15, lc = lane >> 4;

    f32x4 acc[2][2] = {};

    for (int k0 = 0; k0 < 1024; k0 += 32) {
        const int seg = k0 >> 8, kb = k0 & 255;
        const float* Asrc = (seg == 0) ? h : (seg == 1) ? mixed : (seg == 2) ? php : summ;
        {
            int row = tid >> 2, cb = tid & 3;
            int rs = bm + row;
            if (seg == 2) rs >>= 4;
            const float* src = Asrc + (size_t)rs * DS_ + kb + cb * 8;
            float4 u = *reinterpret_cast<const float4*>(src);
            float4 w = *reinterpret_cast<const float4*>(src + 4);
            uint4 g;
            g.x = pack2(u.x, u.y); g.y = pack2(u.z, u.w);
            g.z = pack2(w.x, w.y); g.w = pack2(w.z, w.w);
            *reinterpret_cast<uint4*>(smA + row * 64 + swz(row, cb) * 16) = g;
        }
        {
            int row = tid >> 2, cb = tid & 3;
            uint4 g = *reinterpret_cast<const uint4*>(
                W1t + (size_t)(bn + row) * 1024 + k0 + cb * 8);
            *reinterpret_cast<uint4*>(smB + row * 64 + swz(row, cb) * 16) = g;
        }
        __syncthreads();

        bf16x8 af[2], bfr[2];
        #pragma unroll
        for (int i = 0; i < 2; ++i) {
            int m = wm * 32 + i * 16 + lr;
            af[i] = *reinterpret_cast<const bf16x8*>(smA + m * 64 + swz(m, lc) * 16);
        }
        #pragma unroll
        for (int j = 0; j < 2; ++j) {
            int n = wn * 32 + j * 16 + lr;
            bfr[j] = *reinterpret_cast<const bf16x8*>(smB + n * 64 + swz(n, lc) * 16);
        }
        #pragma unroll
        for (int i = 0; i < 2; ++i)
            #pragma unroll
            for (int j = 0; j < 2; ++j)
                acc[i][j] = __builtin_amdgcn_mfma_f32_16x16x32_bf16(
                    af[i], bfr[j], acc[i][j], 0, 0, 0);
        __syncthreads();
    }

    #pragma unroll
    for (int i = 0; i < 2; ++i) {
        #pragma unroll
        for (int j = 0; j < 2; ++j) {
            int col = bn + wn * 32 + j * 16 + lr;
            #pragma unroll
            for (int r = 0; r < 4; ++r) {
                int row = bm + wm * 32 + i * 16 + lc * 4 + r;
                t[(size_t)row * DS_ + col] = tanhf(acc[i][j][r] + b1[col]);
            }
        }
    }
}

// ---------------------------------------------------------------------------
// Banded scores via MFMA: scores[t, l] = (q[t] . k[t-64+l]) * scale
// One block per 32 tokens; key window = 96 rows (95 used, neg rows clamped,
// masked later in select_k). 4 waves x 3 tiles = 12 (qt,kt) 16x16 tiles.
// ---------------------------------------------------------------------------
__global__ __launch_bounds__(256) void scores_k(
    const float* __restrict__ qkv, float* __restrict__ scores)
{
    __shared__ __align__(16) unsigned char smem[32 * 64 + 96 * 64];
    __shared__ float Sld[32][97];
    unsigned char* smA = smem;            // Q chunk: 32 rows x 32 bf16
    unsigned char* smB = smem + 32 * 64;  // K chunk: 96 rows x 32 bf16

    const int bid = blockIdx.x;                    // 256 blocks
    const int blk = (bid & 7) * 32 + (bid >> 3);   // XCD swizzle (8 x 32)
    const int t0 = blk * 32;
    const int b  = t0 >> 11;
    const int s0 = t0 & (S_ - 1);
    const int tid = threadIdx.x;
    const int lane = tid & 63, wid = tid >> 6;
    const int lr = lane & 15, lc = lane >> 4;
    const int qt  = wid & 1;
    const int ktb = (wid >> 1) * 3;

    const float* qbase = qkv + (size_t)t0 * 768;
    const float* kbase = qkv + (size_t)b * S_ * 768 + 256;

    f32x4 acc[3] = {};

    for (int k0 = 0; k0 < 256; k0 += 32) {
        #pragma unroll
        for (int i = 0; i < 2; ++i) {
            int e = tid + i * 256;
            const float* src;
            unsigned char* dst;
            if (e < 128) {
                int row = e >> 2, cb = e & 3;
                src = qbase + (size_t)row * 768 + k0 + cb * 8;
                dst = smA + row * 64 + swz(row, cb) * 16;
            } else {
                int eb = e - 128;
                int row = eb >> 2, cb = eb & 3;
                int krow = s0 - 64 + row;
                if (krow < 0) krow = 0;
                src = kbase + (size_t)krow * 768 + k0 + cb * 8;
                dst = smB + row * 64 + swz(row, cb) * 16;
            }
            float4 u = *reinterpret_cast<const float4*>(src);
            float4 w = *reinterpret_cast<const float4*>(src + 4);
            uint4 g;
            g.x = pack2(u.x, u.y); g.y = pack2(u.z, u.w);
            g.z = pack2(w.x, w.y); g.w = pack2(w.z, w.w);
            *reinterpret_cast<uint4*>(dst) = g;
        }
        __syncthreads();

        bf16x8 af, bfr[3];
        {
            int m = qt * 16 + lr;
            af = *reinterpret_cast<const bf16x8*>(smA + m * 64 + swz(m, lc) * 16);
        }
        #pragma unroll
        for (int j = 0; j < 3; ++j) {
            int n = (ktb + j) * 16 + lr;
            bfr[j] = *reinterpret_cast<const bf16x8*>(smB + n * 64 + swz(n, lc) * 16);
        }
        #pragma unroll
        for (int j = 0; j < 3; ++j)
            acc[j] = __builtin_amdgcn_mfma_f32_16x16x32_bf16(af, bfr[j], acc[j], 0, 0, 0);
        __syncthreads();
    }

    #pragma unroll
    for (int j = 0; j < 3; ++j) {
        int col = (ktb + j) * 16 + lr;
        #pragma unroll
        for (int r = 0; r < 4; ++r) {
            int row = qt * 16 + lc * 4 + r;
            Sld[row][col] = acc[j][r];
        }
    }
    __syncthreads();

    #pragma unroll
    for (int it = 0; it < 8; ++it) {
        int e = tid + it * 256;
        int i = e >> 6, l = e & 63;
        scores[(size_t)(t0 + i) * 64 + l] = Sld[i][i + l] * 0.0625f;
    }
}

// ---------------------------------------------------------------------------
// Top-8 select + softmax + V-sum, reading precomputed scores[M][64].
// 4 waves/block = 4 tokens; butterfly argmax x8 (low-index tie-break).
// ---------------------------------------------------------------------------
__global__ __launch_bounds__(256) void select_k(
    const float* __restrict__ scores, const float* __restrict__ qkv,
    float* __restrict__ summ)
{
    const int bid = blockIdx.x;                       // 2048 blocks
    const int sb  = (bid & 7) * 256 + (bid >> 3);     // bijective XCD swizzle
    const int m   = sb * 4 + (threadIdx.x >> 6);
    const int b = m >> 11;
    const int s = m & (S_ - 1);
    const int lane = threadIdx.x & 63;

    float sc = (s - LB_ + lane >= 0) ? scores[(size_t)m * 64 + lane] : -INFINITY;

    float vals[TOPK_]; int idxs[TOPK_];
    #pragma unroll
    for (int t = 0; t < TOPK_; ++t) {
        float mv = sc; int mi = lane;
        #pragma unroll
        for (int off = 32; off; off >>= 1) {
            float ov = __shfl_xor(mv, off);
            int   oi = __shfl_xor(mi, off);
            if (ov > mv || (ov == mv && oi < mi)) { mv = ov; mi = oi; }
        }
        vals[t] = mv; idxs[t] = mi;
        if (lane == mi) sc = -INFINITY;
    }

    const float mref = (vals[0] == -INFINITY) ? 0.f : vals[0];
    float e[TOPK_], ssum = 0.f;
    #pragma unroll
    for (int t = 0; t < TOPK_; ++t) { e[t] = expf(vals[t] - mref); ssum += e[t]; }
    const float inv = 1.f / fmaxf(ssum, 1e-30f);

    float out[4] = {0.f, 0.f, 0.f, 0.f};
    #pragma unroll
    for (int t = 0; t < TOPK_; ++t) {
        float wt = e[t] * inv;
        int tok = s - LB_ + idxs[t];
        tok = min(max(tok, 0), S_ - 1);
        const float* vr = qkv + ((size_t)(b * S_) + tok) * 768 + 512;
        #pragma unroll
        for (int i = 0; i < 4; ++i) out[i] += wt * vr[lane + i * 64];
    }
    #pragma unroll
    for (int i = 0; i < 4; ++i)
        summ[(size_t)m * DS_ + lane + i * 64] = out[i];
}

// ---------------------------------------------------------------------------
// Weight prep: out_bf16[N][K] = bf16(in_f32[K][N])
// ---------------------------------------------------------------------------
__global__ __launch_bounds__(256) void transpose_cvt_k(
    const float* __restrict__ in, unsigned short* __restrict__ out, int K, int N)
{
    __shared__ float t[32][33];
    const int k0 = blockIdx.y * 32, n0 = blockIdx.x * 32;
    const int tx = threadIdx.x & 31, ty = threadIdx.x >> 5;
    #pragma unroll
    for (int r = 0; r < 32; r += 8)
        t[ty + r][tx] = in[(size_t)(k0 + ty + r) * N + n0 + tx];
    __syncthreads();
    #pragma unroll
    for (int r = 0; r < 32; r += 8)
        out[(size_t)(n0 + ty + r) * K + k0 + tx] = f2bf(t[tx][ty + r]);
}

__global__ __launch_bounds__(256) void biascat_k(
    const float* __restrict__ bq, const float* __restrict__ bk,
    const float* __restrict__ bv, float* __restrict__ bqkv)
{
    int i = blockIdx.x * 256 + threadIdx.x;
    if (i < 768) {
        float v = (i < 256) ? bq[i] : (i < 512) ? bk[i - 256] : bv[i - 512];
        bqkv[i] = v;
    }
}

// ---------------------------------------------------------------------------
// Causal depthwise conv (K=5) + chunk mean.
// ---------------------------------------------------------------------------
__global__ __launch_bounds__(256) void conv_pool_k(
    const float* __restrict__ h, const float* __restrict__ conv_w,
    const float* __restrict__ conv_b, float* __restrict__ mixed,
    float* __restrict__ cmean)
{
    const int blk = blockIdx.x;          // b*128 + c
    const int d = threadIdx.x;
    const int b = blk >> 7;
    const int s0 = (blk & 127) * 16;
    const float* hb = h + (size_t)b * S_ * DS_;
    float* mb = mixed + (size_t)b * S_ * DS_;

    const float w0 = conv_w[0 * DS_ + d], w1 = conv_w[1 * DS_ + d],
                w2 = conv_w[2 * DS_ + d], w3 = conv_w[3 * DS_ + d],
                w4 = conv_w[4 * DS_ + d];
    const float cb = conv_b[d];

    float a0 = (s0 >= 4) ? hb[(size_t)(s0 - 4) * DS_ + d] : 0.f;
    float a1 = (s0 >= 3) ? hb[(size_t)(s0 - 3) * DS_ + d] : 0.f;
    float a2 = (s0 >= 2) ? hb[(size_t)(s0 - 2) * DS_ + d] : 0.f;
    float a3 = (s0 >= 1) ? hb[(size_t)(s0 - 1) * DS_ + d] : 0.f;

    float sum = 0.f;
    #pragma unroll
    for (int tt = 0; tt < 16; ++tt) {
        int s = s0 + tt;
        float cur = hb[(size_t)s * DS_ + d];
        mb[(size_t)s * DS_ + d] = w0 * a0 + w1 * a1 + w2 * a2 + w3 * a3 + w4 * cur + cb;
        sum += cur;
        a0 = a1; a1 = a2; a2 = a3; a3 = cur;
    }
    cmean[(size_t)blk * DS_ + d] = sum * (1.f / 16.f);
}

// ---------------------------------------------------------------------------
// Halt gate: gate[m] = sigmoid(h[m,:]·Wh[:,2] + bh[2]).
// ---------------------------------------------------------------------------
__global__ __launch_bounds__(256) void gate_k(
    const float* __restrict__ h, const float* __restrict__ Wh,
    const float* __restrict__ bh, float* __restrict__ gate)
{
    const int m = blockIdx.x * 4 + (threadIdx.x >> 6);
    const int lane = threadIdx.x & 63;
    const float* hr = h + (size_t)m * DS_;
    float p = 0.f;
    for (int j = lane; j < DS_; j += 64) p += hr[j] * Wh[j * 3 + 2];
    #pragma unroll
    for (int off = 32; off; off >>= 1) p += __shfl_down(p, off);
    if (lane == 0) gate[m] = 1.f / (1.f + expf(-(p + bh[2])));
}

// ---------------------------------------------------------------------------
extern "C" void kernel_launch(void* const* d_in, const int* in_sizes, int n_in,
                              void* d_out, int out_size, void* d_ws, size_t ws_size,
                              hipStream_t stream)
{
    const float* x      = (const float*)d_in[0];
    const float* Wi     = (const float*)d_in[1];
    const float* bi     = (const float*)d_in[2];
    const float* conv_w = (const float*)d_in[3];
    const float* conv_b = (const float*)d_in[4];
    const float* Wp     = (const float*)d_in[5];
    const float* bp     = (const float*)d_in[6];
    const float* Wh     = (const float*)d_in[7];
    const float* bh     = (const float*)d_in[8];
    const float* Wq     = (const float*)d_in[9];
    const float* bq     = (const float*)d_in[10];
    const float* Wk     = (const float*)d_in[11];
    const float* bk     = (const float*)d_in[12];
    const float* Wv     = (const float*)d_in[13];
    const float* bv     = (const float*)d_in[14];
    const float* W1     = (const float*)d_in[15];
    const float* b1     = (const float*)d_in[16];
    const float* W2     = (const float*)d_in[17];
    const float* b2     = (const float*)d_in[18];
    const float* Wo     = (const float*)d_in[19];
    const float* bo     = (const float*)d_in[20];
    float* out = (float*)d_out;

    float* F     = (float*)d_ws;
    float* h     = F;                            // 8192*256
    float* mixed = h     + (size_t)BS_ * DS_;    // 8192*256
    float* qkv   = mixed + (size_t)BS_ * DS_;    // 8192*768
    float* sm    = qkv   + (size_t)BS_ * 768;    // 8192*256
    float* tb    = sm    + (size_t)BS_ * DS_;    // 8192*256
    float* cmean = tb    + (size_t)BS_ * DS_;    // 512*256
    float* php   = cmean + (size_t)512 * DS_;    // 512*256
    float* gate  = php   + (size_t)512 * DS_;    // 8192
    float* bqkv  = gate  + BS_;                  // 768
    float* scores = tb;   // 8192*64, liveness disjoint from tb
    unsigned short* U = (unsigned short*)(bqkv + 768);
    unsigned short* Wit   = U;                          // 256 x 1024
    unsigned short* Wqkvt = Wit   + (size_t)256 * 1024; // 768 x 256
    unsigned short* Wpt   = Wqkvt + (size_t)768 * 256;  // 256 x 256
    unsigned short* W1t   = Wpt   + (size_t)256 * 256;  // 256 x 1024
    unsigned short* W2t   = W1t   + (size_t)256 * 1024; // 256 x 256
    unsigned short* Wot   = W2t   + (size_t)256 * 256;  // 1024 x 256

    dim3 blk(256);

    // ---- weight prep ----
    transpose_cvt_k<<<dim3(256 / 32, 1024 / 32), blk, 0, stream>>>(Wi, Wit, 1024, 256);
    transpose_cvt_k<<<dim3(256 / 32, 256 / 32),  blk, 0, stream>>>(Wq, Wqkvt,              256, 256);
    transpose_cvt_k<<<dim3(256 / 32, 256 / 32),  blk, 0, stream>>>(Wk, Wqkvt + 256 * 256,  256, 256);
    transpose_cvt_k<<<dim3(256 / 32, 256 / 32),  blk, 0, stream>>>(Wv, Wqkvt + 512 * 256,  256, 256);
    transpose_cvt_k<<<dim3(256 / 32, 256 / 32),  blk, 0, stream>>>(Wp, Wpt, 256, 256);
    transpose_cvt_k<<<dim3(256 / 32, 1024 / 32), blk, 0, stream>>>(W1, W1t, 1024, 256);
    transpose_cvt_k<<<dim3(256 / 32, 256 / 32),  blk, 0, stream>>>(W2, W2t, 256, 256);
    transpose_cvt_k<<<dim3(1024 / 32, 256 / 32), blk, 0, stream>>>(Wo, Wot, 256, 1024);
    biascat_k<<<3, blk, 0, stream>>>(bq, bk, bv, bqkv);

    // ---- forward ----
    mm_k<2, 0><<<dim3(4, 128), blk, 0, stream>>>(x, Wit, bi, h, BS_, DM_, DS_, nullptr, nullptr);

    for (int step = 0; step < 2; ++step) {
        conv_pool_k<<<512, blk, 0, stream>>>(h, conv_w, conv_b, mixed, cmean);
        mm_k<2, 0><<<dim3(4, 8), blk, 0, stream>>>(cmean, Wpt, bp, php, 512, DS_, DS_, nullptr, nullptr);
        mm_k<4, 0><<<dim3(12, 64), blk, 0, stream>>>(h, Wqkvt, bqkv, qkv, BS_, DS_, 768, nullptr, nullptr);
        gate_k<<<BS_ / 4, blk, 0, stream>>>(h, Wh, bh, gate);
        scores_k<<<256, blk, 0, stream>>>(qkv, scores);
        select_k<<<2048, blk, 0, stream>>>(scores, qkv, sm);
        mm_ui_k<<<dim3(4, 128), blk, 0, stream>>>(h, mixed, php, sm, W1t, b1, tb);
        mm_k<2, 2><<<dim3(4, 128), blk, 0, stream>>>(tb, W2t, b2, h, BS_, DS_, DS_, h, gate);
    }

    mm_k<4, 3><<<dim3(16, 64), blk, 0, stream>>>(h, Wot, bo, out, BS_, DS_, DM_, x, nullptr);
}

// Round 5
// 192.987 us; speedup vs baseline: 1.9830x; 1.3463x over previous
//
#include <hip/hip_runtime.h>
#include <math.h>

#define B_    4
#define S_    2048
#define BS_   8192       // B_*S_
#define DM_   1024
#define DS_   256
#define LB_   64
#define TOPK_ 8

typedef unsigned short u16;
typedef __bf16 bf16x8 __attribute__((ext_vector_type(8)));
typedef float  f32x4  __attribute__((ext_vector_type(4)));

static __device__ __forceinline__ u16 f2bf(float f) {
    union { float f; unsigned u; } a; a.f = f;
    unsigned u = a.u;
    unsigned r = u + 0x7FFFu + ((u >> 16) & 1u);   // RNE
    return (u16)(r >> 16);
}
static __device__ __forceinline__ float bf2f(u16 v) {
    union { unsigned u; float f; } a; a.u = ((unsigned)v) << 16; return a.f;
}
static __device__ __forceinline__ unsigned pack2(float a, float b) {
    return (unsigned)f2bf(a) | ((unsigned)f2bf(b) << 16);
}
// granule swizzle: 16B granule index within a 64B row
static __device__ __forceinline__ int swz(int row, int cb) {
    return (cb ^ (row & 3) ^ ((row >> 2) & 3)) & 3;
}

// ---------------------------------------------------------------------------
// MFMA bf16 GEMM: C = epi(A_bf16[M,K] @ Bt_bf16[N,K]^T + bias[N])
// MF = M-fragments per wave (2 -> BM=64, 4 -> BM=128). BN=64, BK=32.
// EPI: 0 -> C bf16
//      2 -> C bf16 = bf16(extra0_bf16 + val * extra1[m])   (h += delta*gate)
//      3 -> C f32  = extra0_f32 + val                      (out = x + proj)
// ---------------------------------------------------------------------------
template<int MF, int EPI>
__global__ __launch_bounds__(256) void mm_k(
    const u16* __restrict__ A, const u16* __restrict__ Bt,
    const float* __restrict__ bias, void* __restrict__ Cv,
    int M, int K, int N,
    const void* __restrict__ extra0v, const float* __restrict__ extra1)
{
    constexpr int BM = MF * 32;
    __shared__ __align__(16) unsigned char smem[BM * 64 + 4096];
    unsigned char* smA = smem;
    unsigned char* smB = smem + BM * 64;

    const int tid  = threadIdx.x;
    const int lane = tid & 63;
    const int wid  = tid >> 6;
    const int wm   = wid >> 1, wn = wid & 1;
    const int bm   = blockIdx.y * BM, bn = blockIdx.x * 64;
    const int lr   = lane & 15, lc = lane >> 4;

    f32x4 acc[MF][2] = {};

    for (int k0 = 0; k0 < K; k0 += 32) {
        // stage A: BM rows x 4 granules of 16B (8 bf16)
        #pragma unroll
        for (int i = 0; i < MF / 2; ++i) {
            int e = tid + i * 256;
            int row = e >> 2, cb = e & 3;
            uint4 g = *reinterpret_cast<const uint4*>(
                A + (size_t)(bm + row) * K + k0 + cb * 8);
            *reinterpret_cast<uint4*>(smA + row * 64 + swz(row, cb) * 16) = g;
        }
        // stage B: 64 rows x 4 granules
        {
            int row = tid >> 2, cb = tid & 3;
            uint4 g = *reinterpret_cast<const uint4*>(
                Bt + (size_t)(bn + row) * K + k0 + cb * 8);
            *reinterpret_cast<uint4*>(smB + row * 64 + swz(row, cb) * 16) = g;
        }
        __syncthreads();

        bf16x8 af[MF], bfr[2];
        #pragma unroll
        for (int i = 0; i < MF; ++i) {
            int m = wm * (MF * 16) + i * 16 + lr;
            af[i] = *reinterpret_cast<const bf16x8*>(smA + m * 64 + swz(m, lc) * 16);
        }
        #pragma unroll
        for (int j = 0; j < 2; ++j) {
            int n = wn * 32 + j * 16 + lr;
            bfr[j] = *reinterpret_cast<const bf16x8*>(smB + n * 64 + swz(n, lc) * 16);
        }
        #pragma unroll
        for (int i = 0; i < MF; ++i)
            #pragma unroll
            for (int j = 0; j < 2; ++j)
                acc[i][j] = __builtin_amdgcn_mfma_f32_16x16x32_bf16(
                    af[i], bfr[j], acc[i][j], 0, 0, 0);
        __syncthreads();
    }

    #pragma unroll
    for (int i = 0; i < MF; ++i) {
        #pragma unroll
        for (int j = 0; j < 2; ++j) {
            int col = bn + wn * 32 + j * 16 + lr;
            #pragma unroll
            for (int r = 0; r < 4; ++r) {
                int row = bm + wm * (MF * 16) + i * 16 + lc * 4 + r;
                float val = acc[i][j][r] + bias[col];
                if constexpr (EPI == 2) {
                    const u16* e0 = (const u16*)extra0v;
                    val = bf2f(e0[(size_t)row * N + col]) + val * extra1[row];
                    ((u16*)Cv)[(size_t)row * N + col] = f2bf(val);
                } else if constexpr (EPI == 3) {
                    const float* e0 = (const float*)extra0v;
                    ((float*)Cv)[(size_t)row * N + col] = e0[(size_t)row * N + col] + val;
                } else {
                    ((u16*)Cv)[(size_t)row * N + col] = f2bf(val);
                }
            }
        }
    }
}

// ---------------------------------------------------------------------------
// ui-concat MFMA GEMM + tanh: t = tanh([h|mixed|pb|summ] @ W1 + b1)
// K=1024 (4 bf16 segments of 256), pb[m,:] = php[m>>4,:]. BM=64.
// ---------------------------------------------------------------------------
__global__ __launch_bounds__(256) void mm_ui_k(
    const u16* __restrict__ h, const u16* __restrict__ mixed,
    const u16* __restrict__ php, const u16* __restrict__ summ,
    const u16* __restrict__ W1t, const float* __restrict__ b1,
    u16* __restrict__ t)
{
    __shared__ __align__(16) unsigned char smem[8192];
    unsigned char* smA = smem;
    unsigned char* smB = smem + 4096;

    const int tid  = threadIdx.x;
    const int lane = tid & 63;
    const int wid  = tid >> 6;
    const int wm   = wid >> 1, wn = wid & 1;
    const int bm   = blockIdx.y * 64, bn = blockIdx.x * 64;
    const int lr   = lane & 15, lc = lane >> 4;

    f32x4 acc[2][2] = {};

    for (int k0 = 0; k0 < 1024; k0 += 32) {
        const int seg = k0 >> 8, kb = k0 & 255;
        const u16* Asrc = (seg == 0) ? h : (seg == 1) ? mixed : (seg == 2) ? php : summ;
        {
            int row = tid >> 2, cb = tid & 3;
            int rs = bm + row;
            if (seg == 2) rs >>= 4;
            uint4 g = *reinterpret_cast<const uint4*>(
                Asrc + (size_t)rs * DS_ + kb + cb * 8);
            *reinterpret_cast<uint4*>(smA + row * 64 + swz(row, cb) * 16) = g;
        }
        {
            int row = tid >> 2, cb = tid & 3;
            uint4 g = *reinterpret_cast<const uint4*>(
                W1t + (size_t)(bn + row) * 1024 + k0 + cb * 8);
            *reinterpret_cast<uint4*>(smB + row * 64 + swz(row, cb) * 16) = g;
        }
        __syncthreads();

        bf16x8 af[2], bfr[2];
        #pragma unroll
        for (int i = 0; i < 2; ++i) {
            int m = wm * 32 + i * 16 + lr;
            af[i] = *reinterpret_cast<const bf16x8*>(smA + m * 64 + swz(m, lc) * 16);
        }
        #pragma unroll
        for (int j = 0; j < 2; ++j) {
            int n = wn * 32 + j * 16 + lr;
            bfr[j] = *reinterpret_cast<const bf16x8*>(smB + n * 64 + swz(n, lc) * 16);
        }
        #pragma unroll
        for (int i = 0; i < 2; ++i)
            #pragma unroll
            for (int j = 0; j < 2; ++j)
                acc[i][j] = __builtin_amdgcn_mfma_f32_16x16x32_bf16(
                    af[i], bfr[j], acc[i][j], 0, 0, 0);
        __syncthreads();
    }

    #pragma unroll
    for (int i = 0; i < 2; ++i) {
        #pragma unroll
        for (int j = 0; j < 2; ++j) {
            int col = bn + wn * 32 + j * 16 + lr;
            #pragma unroll
            for (int r = 0; r < 4; ++r) {
                int row = bm + wm * 32 + i * 16 + lc * 4 + r;
                t[(size_t)row * DS_ + col] = f2bf(tanhf(acc[i][j][r] + b1[col]));
            }
        }
    }
}

// ---------------------------------------------------------------------------
// Banded scores via MFMA: scores[t, l] = (q[t] . k[t-64+l]) * scale, f32 out.
// One block per 32 tokens; key window 96 rows (neg rows clamped, masked in
// select_k). qkv is bf16 [M][768].
// ---------------------------------------------------------------------------
__global__ __launch_bounds__(256) void scores_k(
    const u16* __restrict__ qkv, float* __restrict__ scores)
{
    __shared__ __align__(16) unsigned char smem[32 * 64 + 96 * 64];
    __shared__ float Sld[32][97];
    unsigned char* smA = smem;            // Q chunk: 32 rows x 32 bf16
    unsigned char* smB = smem + 32 * 64;  // K chunk: 96 rows x 32 bf16

    const int bid = blockIdx.x;                    // 256 blocks
    const int blk = (bid & 7) * 32 + (bid >> 3);   // XCD swizzle (8 x 32)
    const int t0 = blk * 32;
    const int b  = t0 >> 11;
    const int s0 = t0 & (S_ - 1);
    const int tid = threadIdx.x;
    const int lane = tid & 63, wid = tid >> 6;
    const int lr = lane & 15, lc = lane >> 4;
    const int qt  = wid & 1;
    const int ktb = (wid >> 1) * 3;

    const u16* qbase = qkv + (size_t)t0 * 768;
    const u16* kbase = qkv + (size_t)b * S_ * 768 + 256;

    f32x4 acc[3] = {};

    for (int k0 = 0; k0 < 256; k0 += 32) {
        #pragma unroll
        for (int i = 0; i < 2; ++i) {
            int e = tid + i * 256;
            const u16* src;
            unsigned char* dst;
            if (e < 128) {
                int row = e >> 2, cb = e & 3;
                src = qbase + (size_t)row * 768 + k0 + cb * 8;
                dst = smA + row * 64 + swz(row, cb) * 16;
            } else {
                int eb = e - 128;
                int row = eb >> 2, cb = eb & 3;
                int krow = s0 - 64 + row;
                if (krow < 0) krow = 0;
                src = kbase + (size_t)krow * 768 + k0 + cb * 8;
                dst = smB + row * 64 + swz(row, cb) * 16;
            }
            *reinterpret_cast<uint4*>(dst) = *reinterpret_cast<const uint4*>(src);
        }
        __syncthreads();

        bf16x8 af, bfr[3];
        {
            int m = qt * 16 + lr;
            af = *reinterpret_cast<const bf16x8*>(smA + m * 64 + swz(m, lc) * 16);
        }
        #pragma unroll
        for (int j = 0; j < 3; ++j) {
            int n = (ktb + j) * 16 + lr;
            bfr[j] = *reinterpret_cast<const bf16x8*>(smB + n * 64 + swz(n, lc) * 16);
        }
        #pragma unroll
        for (int j = 0; j < 3; ++j)
            acc[j] = __builtin_amdgcn_mfma_f32_16x16x32_bf16(af, bfr[j], acc[j], 0, 0, 0);
        __syncthreads();
    }

    #pragma unroll
    for (int j = 0; j < 3; ++j) {
        int col = (ktb + j) * 16 + lr;
        #pragma unroll
        for (int r = 0; r < 4; ++r) {
            int row = qt * 16 + lc * 4 + r;
            Sld[row][col] = acc[j][r];
        }
    }
    __syncthreads();

    #pragma unroll
    for (int it = 0; it < 8; ++it) {
        int e = tid + it * 256;
        int i = e >> 6, l = e & 63;
        scores[(size_t)(t0 + i) * 64 + l] = Sld[i][i + l] * 0.0625f;
    }
}

// ---------------------------------------------------------------------------
// Top-8 select + softmax + V-sum. scores f32, V bf16 (from qkv), summ bf16.
// ---------------------------------------------------------------------------
__global__ __launch_bounds__(256) void select_k(
    const float* __restrict__ scores, const u16* __restrict__ qkv,
    u16* __restrict__ summ)
{
    const int bid = blockIdx.x;                       // 2048 blocks
    const int sb  = (bid & 7) * 256 + (bid >> 3);     // bijective XCD swizzle
    const int m   = sb * 4 + (threadIdx.x >> 6);
    const int b = m >> 11;
    const int s = m & (S_ - 1);
    const int lane = threadIdx.x & 63;

    float sc = (s - LB_ + lane >= 0) ? scores[(size_t)m * 64 + lane] : -INFINITY;

    float vals[TOPK_]; int idxs[TOPK_];
    #pragma unroll
    for (int t = 0; t < TOPK_; ++t) {
        float mv = sc; int mi = lane;
        #pragma unroll
        for (int off = 32; off; off >>= 1) {
            float ov = __shfl_xor(mv, off);
            int   oi = __shfl_xor(mi, off);
            if (ov > mv || (ov == mv && oi < mi)) { mv = ov; mi = oi; }
        }
        vals[t] = mv; idxs[t] = mi;
        if (lane == mi) sc = -INFINITY;
    }

    const float mref = (vals[0] == -INFINITY) ? 0.f : vals[0];
    float e[TOPK_], ssum = 0.f;
    #pragma unroll
    for (int t = 0; t < TOPK_; ++t) { e[t] = expf(vals[t] - mref); ssum += e[t]; }
    const float inv = 1.f / fmaxf(ssum, 1e-30f);

    float out[4] = {0.f, 0.f, 0.f, 0.f};
    #pragma unroll
    for (int t = 0; t < TOPK_; ++t) {
        float wt = e[t] * inv;
        int tok = s - LB_ + idxs[t];
        tok = min(max(tok, 0), S_ - 1);
        const u16* vr = qkv + ((size_t)(b * S_) + tok) * 768 + 512;
        #pragma unroll
        for (int i = 0; i < 4; ++i) out[i] += wt * bf2f(vr[lane + i * 64]);
    }
    #pragma unroll
    for (int i = 0; i < 4; ++i)
        summ[(size_t)m * DS_ + lane + i * 64] = f2bf(out[i]);
}

// ---------------------------------------------------------------------------
// Causal depthwise conv (K=5) + chunk mean + fused halt gate.
// One block per (b, chunk of 16); thread = channel d.
// ---------------------------------------------------------------------------
__global__ __launch_bounds__(256) void conv_pool_k(
    const u16* __restrict__ h, const float* __restrict__ conv_w,
    const float* __restrict__ conv_b, const float* __restrict__ Wh,
    const float* __restrict__ bh, u16* __restrict__ mixed,
    u16* __restrict__ cmean, float* __restrict__ gate)
{
    __shared__ float gpart[16][4];
    const int blk = blockIdx.x;          // b*128 + c
    const int d = threadIdx.x;
    const int b = blk >> 7;
    const int s0 = (blk & 127) * 16;
    const u16* hb = h + (size_t)b * S_ * DS_;
    u16* mb = mixed + (size_t)b * S_ * DS_;

    const float w0 = conv_w[0 * DS_ + d], w1 = conv_w[1 * DS_ + d],
                w2 = conv_w[2 * DS_ + d], w3 = conv_w[3 * DS_ + d],
                w4 = conv_w[4 * DS_ + d];
    const float cb = conv_b[d];
    const float whd = Wh[d * 3 + 2];

    float a0 = (s0 >= 4) ? bf2f(hb[(size_t)(s0 - 4) * DS_ + d]) : 0.f;
    float a1 = (s0 >= 3) ? bf2f(hb[(size_t)(s0 - 3) * DS_ + d]) : 0.f;
    float a2 = (s0 >= 2) ? bf2f(hb[(size_t)(s0 - 2) * DS_ + d]) : 0.f;
    float a3 = (s0 >= 1) ? bf2f(hb[(size_t)(s0 - 1) * DS_ + d]) : 0.f;

    float sum = 0.f;
    #pragma unroll
    for (int tt = 0; tt < 16; ++tt) {
        int s = s0 + tt;
        float cur = bf2f(hb[(size_t)s * DS_ + d]);
        mb[(size_t)s * DS_ + d] = f2bf(w0 * a0 + w1 * a1 + w2 * a2 + w3 * a3 + w4 * cur + cb);
        sum += cur;
        float g = cur * whd;
        #pragma unroll
        for (int off = 32; off; off >>= 1) g += __shfl_down(g, off);
        if ((d & 63) == 0) gpart[tt][d >> 6] = g;
        a0 = a1; a1 = a2; a2 = a3; a3 = cur;
    }
    cmean[(size_t)blk * DS_ + d] = f2bf(sum * (1.f / 16.f));
    __syncthreads();
    if (d < 16) {
        float gg = gpart[d][0] + gpart[d][1] + gpart[d][2] + gpart[d][3];
        gate[(size_t)b * S_ + s0 + d] = 1.f / (1.f + expf(-(gg + bh[2])));
    }
}

// ---------------------------------------------------------------------------
// x f32 -> bf16 (8 elems/thread)
// ---------------------------------------------------------------------------
__global__ __launch_bounds__(256) void cvt_bf16_k(
    const float* __restrict__ in, u16* __restrict__ out, int n)
{
    int i = (blockIdx.x * 256 + threadIdx.x) * 8;
    if (i >= n) return;
    float4 a = *reinterpret_cast<const float4*>(in + i);
    float4 b = *reinterpret_cast<const float4*>(in + i + 4);
    uint4 g;
    g.x = pack2(a.x, a.y); g.y = pack2(a.z, a.w);
    g.z = pack2(b.x, b.y); g.w = pack2(b.z, b.w);
    *reinterpret_cast<uint4*>(out + i) = g;
}

// ---------------------------------------------------------------------------
// All weight transposes (f32[K][N] -> bf16[N][K]) + qkv bias concat, merged.
// Blocks 0..1087: 32x32 transpose tiles; block 1088: bias concat.
// ---------------------------------------------------------------------------
__global__ __launch_bounds__(256) void prep_w_k(
    const float* __restrict__ Wi, const float* __restrict__ Wq,
    const float* __restrict__ Wk, const float* __restrict__ Wv,
    const float* __restrict__ Wp, const float* __restrict__ W1,
    const float* __restrict__ W2, const float* __restrict__ Wo,
    const float* __restrict__ bq, const float* __restrict__ bk,
    const float* __restrict__ bv,
    u16* __restrict__ Wit, u16* __restrict__ Wqkvt, u16* __restrict__ Wpt,
    u16* __restrict__ W1t, u16* __restrict__ W2t, u16* __restrict__ Wot,
    float* __restrict__ bqkv)
{
    const int bid = blockIdx.x;
    if (bid >= 1088) {
        for (int i = threadIdx.x; i < 768; i += 256) {
            float v = (i < 256) ? bq[i] : (i < 512) ? bk[i - 256] : bv[i - 512];
            bqkv[i] = v;
        }
        return;
    }
    const float* in; u16* out; int K, N, t;
    if (bid < 256)      { in = Wi; out = Wit;             K = 1024; N = 256;  t = bid; }
    else if (bid < 320) { in = Wq; out = Wqkvt;           K = 256;  N = 256;  t = bid - 256; }
    else if (bid < 384) { in = Wk; out = Wqkvt + 256*256; K = 256;  N = 256;  t = bid - 320; }
    else if (bid < 448) { in = Wv; out = Wqkvt + 512*256; K = 256;  N = 256;  t = bid - 384; }
    else if (bid < 512) { in = Wp; out = Wpt;             K = 256;  N = 256;  t = bid - 448; }
    else if (bid < 768) { in = W1; out = W1t;             K = 1024; N = 256;  t = bid - 512; }
    else if (bid < 832) { in = W2; out = W2t;             K = 256;  N = 256;  t = bid - 768; }
    else                { in = Wo; out = Wot;             K = 256;  N = 1024; t = bid - 832; }
    const int tilesX = N >> 5;
    const int n0 = (t % tilesX) * 32, k0 = (t / tilesX) * 32;
    __shared__ float tl[32][33];
    const int cx = threadIdx.x & 31, cy = threadIdx.x >> 5;
    #pragma unroll
    for (int r = 0; r < 32; r += 8)
        tl[cy + r][cx] = in[(size_t)(k0 + cy + r) * N + n0 + cx];
    __syncthreads();
    #pragma unroll
    for (int r = 0; r < 32; r += 8)
        out[(size_t)(n0 + cy + r) * K + k0 + cx] = f2bf(tl[cx][cy + r]);
}

// ---------------------------------------------------------------------------
extern "C" void kernel_launch(void* const* d_in, const int* in_sizes, int n_in,
                              void* d_out, int out_size, void* d_ws, size_t ws_size,
                              hipStream_t stream)
{
    const float* x      = (const float*)d_in[0];
    const float* Wi     = (const float*)d_in[1];
    const float* bi     = (const float*)d_in[2];
    const float* conv_w = (const float*)d_in[3];
    const float* conv_b = (const float*)d_in[4];
    const float* Wp     = (const float*)d_in[5];
    const float* bp     = (const float*)d_in[6];
    const float* Wh     = (const float*)d_in[7];
    const float* bh     = (const float*)d_in[8];
    const float* Wq     = (const float*)d_in[9];
    const float* bq     = (const float*)d_in[10];
    const float* Wk     = (const float*)d_in[11];
    const float* bk     = (const float*)d_in[12];
    const float* Wv     = (const float*)d_in[13];
    const float* bv     = (const float*)d_in[14];
    const float* W1     = (const float*)d_in[15];
    const float* b1     = (const float*)d_in[16];
    const float* W2     = (const float*)d_in[17];
    const float* b2     = (const float*)d_in[18];
    const float* Wo     = (const float*)d_in[19];
    const float* bo     = (const float*)d_in[20];
    float* out = (float*)d_out;

    char* p = (char*)d_ws;
    auto alloc = [&](size_t bytes) { char* r = p; p += (bytes + 255) & ~(size_t)255; return r; };

    u16*  xb     = (u16*)alloc((size_t)BS_ * DM_ * 2);   // 16.8 MB
    u16*  h      = (u16*)alloc((size_t)BS_ * DS_ * 2);
    u16*  mixed  = (u16*)alloc((size_t)BS_ * DS_ * 2);
    u16*  qkv    = (u16*)alloc((size_t)BS_ * 768 * 2);
    u16*  sm     = (u16*)alloc((size_t)BS_ * DS_ * 2);
    u16*  tb     = (u16*)alloc((size_t)BS_ * DS_ * 2);
    u16*  cmean  = (u16*)alloc((size_t)512 * DS_ * 2);
    u16*  php    = (u16*)alloc((size_t)512 * DS_ * 2);
    float* gate  = (float*)alloc((size_t)BS_ * 4);
    float* scores= (float*)alloc((size_t)BS_ * 64 * 4);
    float* bqkv  = (float*)alloc(768 * 4);
    u16* Wit     = (u16*)alloc((size_t)256 * 1024 * 2);
    u16* Wqkvt   = (u16*)alloc((size_t)768 * 256 * 2);
    u16* Wpt     = (u16*)alloc((size_t)256 * 256 * 2);
    u16* W1t     = (u16*)alloc((size_t)256 * 1024 * 2);
    u16* W2t     = (u16*)alloc((size_t)256 * 256 * 2);
    u16* Wot     = (u16*)alloc((size_t)1024 * 256 * 2);

    dim3 blk(256);

    // ---- prep ----
    cvt_bf16_k<<<4096, blk, 0, stream>>>(x, xb, BS_ * DM_);
    prep_w_k<<<1089, blk, 0, stream>>>(Wi, Wq, Wk, Wv, Wp, W1, W2, Wo, bq, bk, bv,
                                       Wit, Wqkvt, Wpt, W1t, W2t, Wot, bqkv);

    // ---- forward ----
    // h = x @ Wi + bi
    mm_k<2, 0><<<dim3(4, 128), blk, 0, stream>>>(xb, Wit, bi, h, BS_, DM_, DS_, nullptr, nullptr);

    for (int step = 0; step < 2; ++step) {
        conv_pool_k<<<512, blk, 0, stream>>>(h, conv_w, conv_b, Wh, bh, mixed, cmean, gate);
        mm_k<2, 0><<<dim3(4, 8), blk, 0, stream>>>(cmean, Wpt, bp, php, 512, DS_, DS_, nullptr, nullptr);
        mm_k<4, 0><<<dim3(12, 64), blk, 0, stream>>>(h, Wqkvt, bqkv, qkv, BS_, DS_, 768, nullptr, nullptr);
        scores_k<<<256, blk, 0, stream>>>(qkv, scores);
        select_k<<<2048, blk, 0, stream>>>(scores, qkv, sm);
        mm_ui_k<<<dim3(4, 128), blk, 0, stream>>>(h, mixed, php, sm, W1t, b1, tb);
        // h = h + (tanh(ui@W1+b1) @ W2 + b2) * gate
        mm_k<2, 2><<<dim3(4, 128), blk, 0, stream>>>(tb, W2t, b2, h, BS_, DS_, DS_, h, gate);
    }

    // out = x + h @ Wo + bo
    mm_k<4, 3><<<dim3(16, 64), blk, 0, stream>>>(h, Wot, bo, out, BS_, DS_, DM_, x, nullptr);
}

// Round 6
// 186.279 us; speedup vs baseline: 2.0544x; 1.0360x over previous
//
#include <hip/hip_runtime.h>
#include <math.h>

#define B_    4
#define S_    2048
#define BS_   8192       // B_*S_
#define DM_   1024
#define DS_   256
#define LB_   64
#define TOPK_ 8

typedef unsigned short u16;
typedef __bf16 bf16x8 __attribute__((ext_vector_type(8)));
typedef float  f32x4  __attribute__((ext_vector_type(4)));

static __device__ __forceinline__ u16 f2bf(float f) {
    union { float f; unsigned u; } a; a.f = f;
    unsigned u = a.u;
    unsigned r = u + 0x7FFFu + ((u >> 16) & 1u);   // RNE
    return (u16)(r >> 16);
}
static __device__ __forceinline__ float bf2f(u16 v) {
    union { unsigned u; float f; } a; a.u = ((unsigned)v) << 16; return a.f;
}
static __device__ __forceinline__ unsigned pack2(float a, float b) {
    return (unsigned)f2bf(a) | ((unsigned)f2bf(b) << 16);
}
// 16B-granule swizzle within a 64B row (4 granules)
static __device__ __forceinline__ int swz(int row, int cb) {
    return (cb ^ (row & 3) ^ ((row >> 2) & 3)) & 3;
}

// ---------------------------------------------------------------------------
// MFMA bf16 GEMM, BK=128: C = epi(A_bf16[M,K] @ Bt_bf16[N,K]^T + bias[N])
// MF = M-frags/wave (2 -> BM=64, 4 -> BM=128). BN=64. 256 thr = 4 waves (2x2).
// LDS rows are 256B (16 granules), swizzled g^(row&15): staging writes and
// fragment reads both conflict-free. 1-D grid, XCD-chunked (nb % 8 == 0).
// EPI: 0 -> C bf16 | 2 -> C bf16 = extra0_bf16 + val*extra1[m] | 3 -> C f32 =
// extra0_bf16 + val.
// ---------------------------------------------------------------------------
template<int MF, int EPI>
__global__ __launch_bounds__(256) void mm_k(
    const u16* __restrict__ A, const u16* __restrict__ Bt,
    const float* __restrict__ bias, void* __restrict__ Cv,
    int M, int K, int N, int gx,
    const void* __restrict__ extra0v, const float* __restrict__ extra1)
{
    constexpr int BM = MF * 32;
    __shared__ __align__(16) unsigned char smem[BM * 256 + 64 * 256];
    unsigned char* smA = smem;
    unsigned char* smB = smem + BM * 256;

    const int nb  = gridDim.x;
    const int per = nb >> 3;
    const int id  = blockIdx.x;
    const int nid = (id & 7) * per + (id >> 3);   // bijective XCD chunking
    const int bx  = nid % gx, by = nid / gx;

    const int tid  = threadIdx.x;
    const int lane = tid & 63, wid = tid >> 6;
    const int wm   = wid >> 1, wn = wid & 1;
    const int bm   = by * BM, bn = bx * 64;
    const int lr   = lane & 15, lc = lane >> 4;

    f32x4 acc[MF][2] = {};

    for (int k0 = 0; k0 < K; k0 += 128) {
        // stage A: BM rows x 16 granules
        #pragma unroll
        for (int i = 0; i < MF * 2; ++i) {
            int e = tid + i * 256;
            int row = e >> 4, g = e & 15;
            uint4 v = *reinterpret_cast<const uint4*>(
                A + (size_t)(bm + row) * K + k0 + g * 8);
            *reinterpret_cast<uint4*>(smA + row * 256 + ((g ^ (row & 15)) * 16)) = v;
        }
        // stage B: 64 rows x 16 granules
        #pragma unroll
        for (int i = 0; i < 4; ++i) {
            int e = tid + i * 256;
            int row = e >> 4, g = e & 15;
            uint4 v = *reinterpret_cast<const uint4*>(
                Bt + (size_t)(bn + row) * K + k0 + g * 8);
            *reinterpret_cast<uint4*>(smB + row * 256 + ((g ^ (row & 15)) * 16)) = v;
        }
        __syncthreads();

        #pragma unroll
        for (int kk = 0; kk < 4; ++kk) {
            bf16x8 af[MF], bfr[2];
            #pragma unroll
            for (int i = 0; i < MF; ++i) {
                int m = wm * (MF * 16) + i * 16 + lr;
                af[i] = *reinterpret_cast<const bf16x8*>(
                    smA + m * 256 + (((kk * 4 + lc) ^ (m & 15)) * 16));
            }
            #pragma unroll
            for (int j = 0; j < 2; ++j) {
                int n = wn * 32 + j * 16 + lr;
                bfr[j] = *reinterpret_cast<const bf16x8*>(
                    smB + n * 256 + (((kk * 4 + lc) ^ (n & 15)) * 16));
            }
            #pragma unroll
            for (int i = 0; i < MF; ++i)
                #pragma unroll
                for (int j = 0; j < 2; ++j)
                    acc[i][j] = __builtin_amdgcn_mfma_f32_16x16x32_bf16(
                        af[i], bfr[j], acc[i][j], 0, 0, 0);
        }
        __syncthreads();
    }

    #pragma unroll
    for (int i = 0; i < MF; ++i) {
        #pragma unroll
        for (int j = 0; j < 2; ++j) {
            int col = bn + wn * 32 + j * 16 + lr;
            #pragma unroll
            for (int r = 0; r < 4; ++r) {
                int row = bm + wm * (MF * 16) + i * 16 + lc * 4 + r;
                float val = acc[i][j][r] + bias[col];
                if constexpr (EPI == 2) {
                    const u16* e0 = (const u16*)extra0v;
                    val = bf2f(e0[(size_t)row * N + col]) + val * extra1[row];
                    ((u16*)Cv)[(size_t)row * N + col] = f2bf(val);
                } else if constexpr (EPI == 3) {
                    const u16* e0 = (const u16*)extra0v;
                    ((float*)Cv)[(size_t)row * N + col] = bf2f(e0[(size_t)row * N + col]) + val;
                } else {
                    ((u16*)Cv)[(size_t)row * N + col] = f2bf(val);
                }
            }
        }
    }
}

// ---------------------------------------------------------------------------
// ui-concat MFMA GEMM + tanh, BK=128: t = tanh([h|mixed|pb|summ] @ W1 + b1)
// K=1024 (4 bf16 segments of 256), pb[m,:] = php[m>>4,:]. BM=64.
// ---------------------------------------------------------------------------
__global__ __launch_bounds__(256) void mm_ui_k(
    const u16* __restrict__ h, const u16* __restrict__ mixed,
    const u16* __restrict__ php, const u16* __restrict__ summ,
    const u16* __restrict__ W1t, const float* __restrict__ b1,
    u16* __restrict__ t)
{
    __shared__ __align__(16) unsigned char smem[32768];
    unsigned char* smA = smem;
    unsigned char* smB = smem + 16384;

    const int nb  = gridDim.x;
    const int per = nb >> 3;
    const int id  = blockIdx.x;
    const int nid = (id & 7) * per + (id >> 3);
    const int bx  = nid & 3, by = nid >> 2;

    const int tid  = threadIdx.x;
    const int lane = tid & 63, wid = tid >> 6;
    const int wm   = wid >> 1, wn = wid & 1;
    const int bm   = by * 64, bn = bx * 64;
    const int lr   = lane & 15, lc = lane >> 4;

    f32x4 acc[2][2] = {};

    for (int k0 = 0; k0 < 1024; k0 += 128) {
        const int seg = k0 >> 8, kb = k0 & 255;
        const u16* Asrc = (seg == 0) ? h : (seg == 1) ? mixed : (seg == 2) ? php : summ;
        #pragma unroll
        for (int i = 0; i < 4; ++i) {
            int e = tid + i * 256;
            int row = e >> 4, g = e & 15;
            int rs = bm + row;
            if (seg == 2) rs >>= 4;
            uint4 v = *reinterpret_cast<const uint4*>(
                Asrc + (size_t)rs * DS_ + kb + g * 8);
            *reinterpret_cast<uint4*>(smA + row * 256 + ((g ^ (row & 15)) * 16)) = v;
        }
        #pragma unroll
        for (int i = 0; i < 4; ++i) {
            int e = tid + i * 256;
            int row = e >> 4, g = e & 15;
            uint4 v = *reinterpret_cast<const uint4*>(
                W1t + (size_t)(bn + row) * 1024 + k0 + g * 8);
            *reinterpret_cast<uint4*>(smB + row * 256 + ((g ^ (row & 15)) * 16)) = v;
        }
        __syncthreads();

        #pragma unroll
        for (int kk = 0; kk < 4; ++kk) {
            bf16x8 af[2], bfr[2];
            #pragma unroll
            for (int i = 0; i < 2; ++i) {
                int m = wm * 32 + i * 16 + lr;
                af[i] = *reinterpret_cast<const bf16x8*>(
                    smA + m * 256 + (((kk * 4 + lc) ^ (m & 15)) * 16));
            }
            #pragma unroll
            for (int j = 0; j < 2; ++j) {
                int n = wn * 32 + j * 16 + lr;
                bfr[j] = *reinterpret_cast<const bf16x8*>(
                    smB + n * 256 + (((kk * 4 + lc) ^ (n & 15)) * 16));
            }
            #pragma unroll
            for (int i = 0; i < 2; ++i)
                #pragma unroll
                for (int j = 0; j < 2; ++j)
                    acc[i][j] = __builtin_amdgcn_mfma_f32_16x16x32_bf16(
                        af[i], bfr[j], acc[i][j], 0, 0, 0);
        }
        __syncthreads();
    }

    #pragma unroll
    for (int i = 0; i < 2; ++i) {
        #pragma unroll
        for (int j = 0; j < 2; ++j) {
            int col = bn + wn * 32 + j * 16 + lr;
            #pragma unroll
            for (int r = 0; r < 4; ++r) {
                int row = bm + wm * 32 + i * 16 + lc * 4 + r;
                t[(size_t)row * DS_ + col] = f2bf(tanhf(acc[i][j][r] + b1[col]));
            }
        }
    }
}

// ---------------------------------------------------------------------------
// Banded scores via MFMA: scores[t, l] = (q[t] . k[t-64+l]) * scale, f32 out.
// ---------------------------------------------------------------------------
__global__ __launch_bounds__(256) void scores_k(
    const u16* __restrict__ qkv, float* __restrict__ scores)
{
    __shared__ __align__(16) unsigned char smem[32 * 64 + 96 * 64];
    __shared__ float Sld[32][97];
    unsigned char* smA = smem;            // Q chunk: 32 rows x 32 bf16
    unsigned char* smB = smem + 32 * 64;  // K chunk: 96 rows x 32 bf16

    const int bid = blockIdx.x;                    // 256 blocks
    const int blk = (bid & 7) * 32 + (bid >> 3);   // XCD swizzle (8 x 32)
    const int t0 = blk * 32;
    const int b  = t0 >> 11;
    const int s0 = t0 & (S_ - 1);
    const int tid = threadIdx.x;
    const int lane = tid & 63, wid = tid >> 6;
    const int lr = lane & 15, lc = lane >> 4;
    const int qt  = wid & 1;
    const int ktb = (wid >> 1) * 3;

    const u16* qbase = qkv + (size_t)t0 * 768;
    const u16* kbase = qkv + (size_t)b * S_ * 768 + 256;

    f32x4 acc[3] = {};

    for (int k0 = 0; k0 < 256; k0 += 32) {
        #pragma unroll
        for (int i = 0; i < 2; ++i) {
            int e = tid + i * 256;
            const u16* src;
            unsigned char* dst;
            if (e < 128) {
                int row = e >> 2, cb = e & 3;
                src = qbase + (size_t)row * 768 + k0 + cb * 8;
                dst = smA + row * 64 + swz(row, cb) * 16;
            } else {
                int eb = e - 128;
                int row = eb >> 2, cb = eb & 3;
                int krow = s0 - 64 + row;
                if (krow < 0) krow = 0;
                src = kbase + (size_t)krow * 768 + k0 + cb * 8;
                dst = smB + row * 64 + swz(row, cb) * 16;
            }
            *reinterpret_cast<uint4*>(dst) = *reinterpret_cast<const uint4*>(src);
        }
        __syncthreads();

        bf16x8 af, bfr[3];
        {
            int m = qt * 16 + lr;
            af = *reinterpret_cast<const bf16x8*>(smA + m * 64 + swz(m, lc) * 16);
        }
        #pragma unroll
        for (int j = 0; j < 3; ++j) {
            int n = (ktb + j) * 16 + lr;
            bfr[j] = *reinterpret_cast<const bf16x8*>(smB + n * 64 + swz(n, lc) * 16);
        }
        #pragma unroll
        for (int j = 0; j < 3; ++j)
            acc[j] = __builtin_amdgcn_mfma_f32_16x16x32_bf16(af, bfr[j], acc[j], 0, 0, 0);
        __syncthreads();
    }

    #pragma unroll
    for (int j = 0; j < 3; ++j) {
        int col = (ktb + j) * 16 + lr;
        #pragma unroll
        for (int r = 0; r < 4; ++r) {
            int row = qt * 16 + lc * 4 + r;
            Sld[row][col] = acc[j][r];
        }
    }
    __syncthreads();

    #pragma unroll
    for (int it = 0; it < 8; ++it) {
        int e = tid + it * 256;
        int i = e >> 6, l = e & 63;
        scores[(size_t)(t0 + i) * 64 + l] = Sld[i][i + l] * 0.0625f;
    }
}

// ---------------------------------------------------------------------------
// Top-8 select + softmax + V-sum. scores f32, V bf16 (from qkv), summ bf16.
// ---------------------------------------------------------------------------
__global__ __launch_bounds__(256) void select_k(
    const float* __restrict__ scores, const u16* __restrict__ qkv,
    u16* __restrict__ summ)
{
    const int bid = blockIdx.x;                       // 2048 blocks
    const int sb  = (bid & 7) * 256 + (bid >> 3);     // bijective XCD swizzle
    const int m   = sb * 4 + (threadIdx.x >> 6);
    const int b = m >> 11;
    const int s = m & (S_ - 1);
    const int lane = threadIdx.x & 63;

    float sc = (s - LB_ + lane >= 0) ? scores[(size_t)m * 64 + lane] : -INFINITY;

    float vals[TOPK_]; int idxs[TOPK_];
    #pragma unroll
    for (int t = 0; t < TOPK_; ++t) {
        float mv = sc; int mi = lane;
        #pragma unroll
        for (int off = 32; off; off >>= 1) {
            float ov = __shfl_xor(mv, off);
            int   oi = __shfl_xor(mi, off);
            if (ov > mv || (ov == mv && oi < mi)) { mv = ov; mi = oi; }
        }
        vals[t] = mv; idxs[t] = mi;
        if (lane == mi) sc = -INFINITY;
    }

    const float mref = (vals[0] == -INFINITY) ? 0.f : vals[0];
    float e[TOPK_], ssum = 0.f;
    #pragma unroll
    for (int t = 0; t < TOPK_; ++t) { e[t] = expf(vals[t] - mref); ssum += e[t]; }
    const float inv = 1.f / fmaxf(ssum, 1e-30f);

    float out[4] = {0.f, 0.f, 0.f, 0.f};
    #pragma unroll
    for (int t = 0; t < TOPK_; ++t) {
        float wt = e[t] * inv;
        int tok = s - LB_ + idxs[t];
        tok = min(max(tok, 0), S_ - 1);
        const u16* vr = qkv + ((size_t)(b * S_) + tok) * 768 + 512;
        #pragma unroll
        for (int i = 0; i < 4; ++i) out[i] += wt * bf2f(vr[lane + i * 64]);
    }
    #pragma unroll
    for (int i = 0; i < 4; ++i)
        summ[(size_t)m * DS_ + lane + i * 64] = f2bf(out[i]);
}

// ---------------------------------------------------------------------------
// Causal depthwise conv (K=5) + chunk mean + fused halt gate.
// ---------------------------------------------------------------------------
__global__ __launch_bounds__(256) void conv_pool_k(
    const u16* __restrict__ h, const float* __restrict__ conv_w,
    const float* __restrict__ conv_b, const float* __restrict__ Wh,
    const float* __restrict__ bh, u16* __restrict__ mixed,
    u16* __restrict__ cmean, float* __restrict__ gate)
{
    __shared__ float gpart[16][4];
    const int blk = blockIdx.x;          // b*128 + c
    const int d = threadIdx.x;
    const int b = blk >> 7;
    const int s0 = (blk & 127) * 16;
    const u16* hb = h + (size_t)b * S_ * DS_;
    u16* mb = mixed + (size_t)b * S_ * DS_;

    const float w0 = conv_w[0 * DS_ + d], w1 = conv_w[1 * DS_ + d],
                w2 = conv_w[2 * DS_ + d], w3 = conv_w[3 * DS_ + d],
                w4 = conv_w[4 * DS_ + d];
    const float cb = conv_b[d];
    const float whd = Wh[d * 3 + 2];

    float a0 = (s0 >= 4) ? bf2f(hb[(size_t)(s0 - 4) * DS_ + d]) : 0.f;
    float a1 = (s0 >= 3) ? bf2f(hb[(size_t)(s0 - 3) * DS_ + d]) : 0.f;
    float a2 = (s0 >= 2) ? bf2f(hb[(size_t)(s0 - 2) * DS_ + d]) : 0.f;
    float a3 = (s0 >= 1) ? bf2f(hb[(size_t)(s0 - 1) * DS_ + d]) : 0.f;

    float sum = 0.f;
    #pragma unroll
    for (int tt = 0; tt < 16; ++tt) {
        int s = s0 + tt;
        float cur = bf2f(hb[(size_t)s * DS_ + d]);
        mb[(size_t)s * DS_ + d] = f2bf(w0 * a0 + w1 * a1 + w2 * a2 + w3 * a3 + w4 * cur + cb);
        sum += cur;
        float g = cur * whd;
        #pragma unroll
        for (int off = 32; off; off >>= 1) g += __shfl_down(g, off);
        if ((d & 63) == 0) gpart[tt][d >> 6] = g;
        a0 = a1; a1 = a2; a2 = a3; a3 = cur;
    }
    cmean[(size_t)blk * DS_ + d] = f2bf(sum * (1.f / 16.f));
    __syncthreads();
    if (d < 16) {
        float gg = gpart[d][0] + gpart[d][1] + gpart[d][2] + gpart[d][3];
        gate[(size_t)b * S_ + s0 + d] = 1.f / (1.f + expf(-(gg + bh[2])));
    }
}

// ---------------------------------------------------------------------------
// Merged prep: blocks 0..4095 cvt x->bf16; 4096..5183 weight transposes;
// 5184 qkv bias concat.
// ---------------------------------------------------------------------------
__global__ __launch_bounds__(256) void prep_all_k(
    const float* __restrict__ x,
    const float* __restrict__ Wi, const float* __restrict__ Wq,
    const float* __restrict__ Wk, const float* __restrict__ Wv,
    const float* __restrict__ Wp, const float* __restrict__ W1,
    const float* __restrict__ W2, const float* __restrict__ Wo,
    const float* __restrict__ bq, const float* __restrict__ bk,
    const float* __restrict__ bv,
    u16* __restrict__ xb,
    u16* __restrict__ Wit, u16* __restrict__ Wqkvt, u16* __restrict__ Wpt,
    u16* __restrict__ W1t, u16* __restrict__ W2t, u16* __restrict__ Wot,
    float* __restrict__ bqkv)
{
    const int bid0 = blockIdx.x;
    if (bid0 < 4096) {
        int i = (bid0 * 256 + threadIdx.x) * 8;
        float4 a = *reinterpret_cast<const float4*>(x + i);
        float4 b = *reinterpret_cast<const float4*>(x + i + 4);
        uint4 g;
        g.x = pack2(a.x, a.y); g.y = pack2(a.z, a.w);
        g.z = pack2(b.x, b.y); g.w = pack2(b.z, b.w);
        *reinterpret_cast<uint4*>(xb + i) = g;
        return;
    }
    const int bid = bid0 - 4096;
    if (bid >= 1088) {
        for (int i = threadIdx.x; i < 768; i += 256) {
            float v = (i < 256) ? bq[i] : (i < 512) ? bk[i - 256] : bv[i - 512];
            bqkv[i] = v;
        }
        return;
    }
    const float* in; u16* out; int K, N, t;
    if (bid < 256)      { in = Wi; out = Wit;             K = 1024; N = 256;  t = bid; }
    else if (bid < 320) { in = Wq; out = Wqkvt;           K = 256;  N = 256;  t = bid - 256; }
    else if (bid < 384) { in = Wk; out = Wqkvt + 256*256; K = 256;  N = 256;  t = bid - 320; }
    else if (bid < 448) { in = Wv; out = Wqkvt + 512*256; K = 256;  N = 256;  t = bid - 384; }
    else if (bid < 512) { in = Wp; out = Wpt;             K = 256;  N = 256;  t = bid - 448; }
    else if (bid < 768) { in = W1; out = W1t;             K = 1024; N = 256;  t = bid - 512; }
    else if (bid < 832) { in = W2; out = W2t;             K = 256;  N = 256;  t = bid - 768; }
    else                { in = Wo; out = Wot;             K = 256;  N = 1024; t = bid - 832; }
    const int tilesX = N >> 5;
    const int n0 = (t % tilesX) * 32, k0 = (t / tilesX) * 32;
    __shared__ float tl[32][33];
    const int cx = threadIdx.x & 31, cy = threadIdx.x >> 5;
    #pragma unroll
    for (int r = 0; r < 32; r += 8)
        tl[cy + r][cx] = in[(size_t)(k0 + cy + r) * N + n0 + cx];
    __syncthreads();
    #pragma unroll
    for (int r = 0; r < 32; r += 8)
        out[(size_t)(n0 + cy + r) * K + k0 + cx] = f2bf(tl[cx][cy + r]);
}

// ---------------------------------------------------------------------------
extern "C" void kernel_launch(void* const* d_in, const int* in_sizes, int n_in,
                              void* d_out, int out_size, void* d_ws, size_t ws_size,
                              hipStream_t stream)
{
    const float* x      = (const float*)d_in[0];
    const float* Wi     = (const float*)d_in[1];
    const float* bi     = (const float*)d_in[2];
    const float* conv_w = (const float*)d_in[3];
    const float* conv_b = (const float*)d_in[4];
    const float* Wp     = (const float*)d_in[5];
    const float* bp     = (const float*)d_in[6];
    const float* Wh     = (const float*)d_in[7];
    const float* bh     = (const float*)d_in[8];
    const float* Wq     = (const float*)d_in[9];
    const float* bq     = (const float*)d_in[10];
    const float* Wk     = (const float*)d_in[11];
    const float* bk     = (const float*)d_in[12];
    const float* Wv     = (const float*)d_in[13];
    const float* bv     = (const float*)d_in[14];
    const float* W1     = (const float*)d_in[15];
    const float* b1     = (const float*)d_in[16];
    const float* W2     = (const float*)d_in[17];
    const float* b2     = (const float*)d_in[18];
    const float* Wo     = (const float*)d_in[19];
    const float* bo     = (const float*)d_in[20];
    float* out = (float*)d_out;

    char* p = (char*)d_ws;
    auto alloc = [&](size_t bytes) { char* r = p; p += (bytes + 255) & ~(size_t)255; return r; };

    u16*  xb     = (u16*)alloc((size_t)BS_ * DM_ * 2);
    u16*  h      = (u16*)alloc((size_t)BS_ * DS_ * 2);
    u16*  mixed  = (u16*)alloc((size_t)BS_ * DS_ * 2);
    u16*  qkv    = (u16*)alloc((size_t)BS_ * 768 * 2);
    u16*  sm     = (u16*)alloc((size_t)BS_ * DS_ * 2);
    u16*  tb     = (u16*)alloc((size_t)BS_ * DS_ * 2);
    u16*  cmean  = (u16*)alloc((size_t)512 * DS_ * 2);
    u16*  php    = (u16*)alloc((size_t)512 * DS_ * 2);
    float* gate  = (float*)alloc((size_t)BS_ * 4);
    float* scores= (float*)alloc((size_t)BS_ * 64 * 4);
    float* bqkv  = (float*)alloc(768 * 4);
    u16* Wit     = (u16*)alloc((size_t)256 * 1024 * 2);
    u16* Wqkvt   = (u16*)alloc((size_t)768 * 256 * 2);
    u16* Wpt     = (u16*)alloc((size_t)256 * 256 * 2);
    u16* W1t     = (u16*)alloc((size_t)256 * 1024 * 2);
    u16* W2t     = (u16*)alloc((size_t)256 * 256 * 2);
    u16* Wot     = (u16*)alloc((size_t)1024 * 256 * 2);

    dim3 blk(256);

    // ---- prep (cvt x + all weight transposes + bias concat) ----
    prep_all_k<<<5185, blk, 0, stream>>>(x, Wi, Wq, Wk, Wv, Wp, W1, W2, Wo,
                                         bq, bk, bv, xb,
                                         Wit, Wqkvt, Wpt, W1t, W2t, Wot, bqkv);

    // ---- forward ----
    // h = x @ Wi + bi   (BM=64, grid 4x128 -> 512 blocks)
    mm_k<2, 0><<<512, blk, 0, stream>>>(xb, Wit, bi, h, BS_, DM_, DS_, 4, nullptr, nullptr);

    for (int step = 0; step < 2; ++step) {
        conv_pool_k<<<512, blk, 0, stream>>>(h, conv_w, conv_b, Wh, bh, mixed, cmean, gate);
        mm_k<2, 0><<<32, blk, 0, stream>>>(cmean, Wpt, bp, php, 512, DS_, DS_, 4, nullptr, nullptr);
        mm_k<4, 0><<<768, blk, 0, stream>>>(h, Wqkvt, bqkv, qkv, BS_, DS_, 768, 12, nullptr, nullptr);
        scores_k<<<256, blk, 0, stream>>>(qkv, scores);
        select_k<<<2048, blk, 0, stream>>>(scores, qkv, sm);
        mm_ui_k<<<512, blk, 0, stream>>>(h, mixed, php, sm, W1t, b1, tb);
        // h = h + (tanh(ui@W1+b1) @ W2 + b2) * gate
        mm_k<2, 2><<<512, blk, 0, stream>>>(tb, W2t, b2, h, BS_, DS_, DS_, 4, h, gate);
    }

    // out = x + h @ Wo + bo   (BM=128, grid 16x64 -> 1024 blocks)
    mm_k<4, 3><<<1024, blk, 0, stream>>>(h, Wot, bo, out, BS_, DS_, DM_, 16, xb, nullptr);
}